// Round 5
// baseline (18.679 us; speedup 1.0000x reference)
//
#include <hip/hip_runtime.h>

#define BB 8
#define NN 512
#define DD 128
#define NCH 16           // n-chunks
#define CHN (NN / NCH)   // 32 n per chunk
#define NP  (CHN + 4)    // 36: bank stride 4 -> max 2-way LDS conflicts (free)
#define NPAIR 10         // triangular 32x32 tile pairs (it <= jt)

#define LOG2E 1.4426950408889634f
#define LN2   0.6931471805599453f

// Kernel 1: partial (sum_e, sum_e*w') over one 32-n chunk for one triangular
// 32x32 tile pair. grid = 8*10*16 = 1280 = 5 blocks/CU exactly (balanced,
// all co-resident at 9.2KB LDS). 2x2 register blocking keeps LDS reads at
// 4B/STEP (VALU-bound, not LDS-bound).
// xi pre-scaled by log2e: STEP = v_mul, v_exp(exp2), v_add, v_fma.
// No max subtraction: |w'| <= ~36 for N(0,1) data, exp2 safe in fp32.
__global__ __launch_bounds__(256) void sop_part(const float* __restrict__ x,
                                                float2* __restrict__ part) {
    int bid = blockIdx.x;
    int nc   = bid & 15;
    int rest = bid >> 4;
    int p    = rest % NPAIR;
    int b    = rest / NPAIR;
    int it = (p >= 4) + (p >= 7) + (p >= 9);
    int jbase = (it == 0) ? 0 : (it == 1) ? 4 : (it == 2) ? 7 : 9;
    int jt = it + (p - jbase);
    int i0 = it * 32, j0 = jt * 32, n0 = nc * CHN;

    __shared__ float xi[32][NP];   // scaled by log2e
    __shared__ float xj[32][NP];

    const float* xb = x + ((size_t)b * NN + n0) * DD;
    int tid = threadIdx.x;

    // Stage 32 i-cols + 32 j-cols for 32 n, transposed to [d][nn].
    // d = idx&31 -> 128B coalesced global segments.
    for (int k = 0; k < 4; ++k) {
        int idx = tid + (k << 8);   // 0..1023 = 32 d x 32 nn
        int d  = idx & 31;
        int nn = idx >> 5;
        xi[d][nn] = xb[nn * DD + i0 + d] * LOG2E;
        xj[d][nn] = xb[nn * DD + j0 + d];
    }
    __syncthreads();

    int tj = tid & 15, ti = tid >> 4;
    const float* xiA = xi[ti];
    const float* xiB = xi[ti + 16];
    const float* xjA = xj[tj];
    const float* xjB = xj[tj + 16];

    float sAA = 0.f, sAB = 0.f, sBA = 0.f, sBB = 0.f;
    float wAA = 0.f, wAB = 0.f, wBA = 0.f, wBB = 0.f;

#pragma unroll
    for (int nn = 0; nn < CHN; nn += 4) {
        float4 a0 = *(const float4*)&xiA[nn];
        float4 a1 = *(const float4*)&xiB[nn];
        float4 c0 = *(const float4*)&xjA[nn];
        float4 c1 = *(const float4*)&xjB[nn];
#define STEP(ax, cx, sv, wv) { float w_ = (ax) * (cx); float e_ = __builtin_amdgcn_exp2f(w_); (sv) += e_; (wv) = fmaf(e_, w_, (wv)); }
        STEP(a0.x, c0.x, sAA, wAA) STEP(a0.y, c0.y, sAA, wAA) STEP(a0.z, c0.z, sAA, wAA) STEP(a0.w, c0.w, sAA, wAA)
        STEP(a0.x, c1.x, sAB, wAB) STEP(a0.y, c1.y, sAB, wAB) STEP(a0.z, c1.z, sAB, wAB) STEP(a0.w, c1.w, sAB, wAB)
        STEP(a1.x, c0.x, sBA, wBA) STEP(a1.y, c0.y, sBA, wBA) STEP(a1.z, c0.z, sBA, wBA) STEP(a1.w, c0.w, sBA, wBA)
        STEP(a1.x, c1.x, sBB, wBB) STEP(a1.y, c1.y, sBB, wBB) STEP(a1.z, c1.z, sBB, wBB) STEP(a1.w, c1.w, sBB, wBB)
#undef STEP
    }

    // partial layout: part[nc][b][p][32*32] {sum_e, sum_e*w'} -> 10.5 MB
    float2* pbase = part + ((size_t)(nc * BB + b) * NPAIR + p) * 1024;
    pbase[ti * 32 + tj]               = make_float2(sAA, wAA);
    pbase[ti * 32 + tj + 16]          = make_float2(sAB, wAB);
    pbase[(ti + 16) * 32 + tj]        = make_float2(sBA, wBA);
    pbase[(ti + 16) * 32 + tj + 16]   = make_float2(sBB, wBB);
}

// Kernel 2: one block per quarter-tile (8 rows of 32). Reduce 16 chunk
// partials (coalesced 512B/wave loads per chunk), un-scale, divide, store
// direct (coalesced) + mirror (4B scatter, cheap).
__global__ __launch_bounds__(256) void sop_fin(const float2* __restrict__ part,
                                               float* __restrict__ out) {
    int bid = blockIdx.x;            // 320 = 8b * 10p * 4q
    int q = bid & 3;
    int t = bid >> 2;
    int p = t % NPAIR;
    int b = t / NPAIR;
    int it = (p >= 4) + (p >= 7) + (p >= 9);
    int jbase = (it == 0) ? 0 : (it == 1) ? 4 : (it == 2) ? 7 : 9;
    int jt = it + (p - jbase);
    int i0 = it * 32, j0 = jt * 32;

    int e = q * 256 + threadIdx.x;   // element in 32x32 tile
    size_t tbase = ((size_t)b * NPAIR + p) * 1024 + e;

    float s = 0.f, w = 0.f;
#pragma unroll
    for (int nc = 0; nc < NCH; ++nc) {
        float2 pp = part[(size_t)nc * (BB * NPAIR * 1024) + tbase];
        s += pp.x;
        w += pp.y;
    }
    float v = w * LN2 / s;

    int ti = e >> 5, tj = e & 31;
    int i = i0 + ti, j = j0 + tj;
    out[((size_t)b * DD + i) * DD + j] = v;
    if (it != jt)
        out[((size_t)b * DD + j) * DD + i] = v;
}

extern "C" void kernel_launch(void* const* d_in, const int* in_sizes, int n_in,
                              void* d_out, int out_size, void* d_ws, size_t ws_size,
                              hipStream_t stream) {
    const float* x = (const float*)d_in[0];
    float* out = (float*)d_out;
    float2* part = (float2*)d_ws;
    (void)in_sizes; (void)n_in; (void)ws_size; (void)out_size;

    sop_part<<<dim3(BB * NPAIR * NCH), dim3(256), 0, stream>>>(x, part);
    sop_fin<<<dim3(BB * NPAIR * 4), dim3(256), 0, stream>>>(part, out);
}